// Round 2
// baseline (966.718 us; speedup 1.0000x reference)
//
#include <hip/hip_runtime.h>
#include <math.h>

#define KVOX 15000
#define TP 35
#define CIN 7
#define CM1 16
#define CM2 64
#define NPTS (KVOX * TP)
#define DD 10
#define HH 400
#define WWID 352
#define EPSBN 1e-5f
#define NB1 1024
#define NBV 3750   // KVOX / 4 voxels-per-block

// ---------------- layer-1 BN stats ----------------
__global__ __launch_bounds__(256) void stats1_kernel(
    const float* __restrict__ feat, const float* __restrict__ W1,
    const float* __restrict__ b1, float* __restrict__ partial1)
{
    __shared__ float w1s[CIN * CM1];
    __shared__ float b1s[CM1];
    __shared__ float red[4][32];
    int tid = threadIdx.x;
    if (tid < CIN * CM1) w1s[tid] = W1[tid];
    if (tid < CM1) b1s[tid] = b1[tid];
    __syncthreads();

    float s[CM1], q[CM1];
#pragma unroll
    for (int c = 0; c < CM1; ++c) { s[c] = 0.f; q[c] = 0.f; }

    for (int i = blockIdx.x * 256 + tid; i < NPTS; i += NB1 * 256) {
        float f[CIN];
#pragma unroll
        for (int j = 0; j < CIN; ++j) f[j] = feat[(size_t)i * CIN + j];
#pragma unroll
        for (int c = 0; c < CM1; ++c) {
            float acc = b1s[c];
#pragma unroll
            for (int j = 0; j < CIN; ++j) acc = fmaf(f[j], w1s[j * CM1 + c], acc);
            float pw = fmaxf(acc, 0.f);
            s[c] += pw; q[c] += pw * pw;
        }
    }
#pragma unroll
    for (int c = 0; c < CM1; ++c) {
#pragma unroll
        for (int off = 32; off > 0; off >>= 1) {
            s[c] += __shfl_xor(s[c], off);
            q[c] += __shfl_xor(q[c], off);
        }
    }
    int wid = tid >> 6, lane = tid & 63;
    if (lane == 0) {
#pragma unroll
        for (int c = 0; c < CM1; ++c) { red[wid][c] = s[c]; red[wid][CM1 + c] = q[c]; }
    }
    __syncthreads();
    if (tid < 32)
        partial1[blockIdx.x * 32 + tid] =
            red[0][tid] + red[1][tid] + red[2][tid] + red[3][tid];
}

__global__ __launch_bounds__(256) void reduce1_kernel(
    const float* __restrict__ partial1, const float* __restrict__ g1,
    const float* __restrict__ be1, float* __restrict__ coef1)
{
    __shared__ float acc[8][32];
    __shared__ float tot[32];
    int tid = threadIdx.x;
    int c = tid & 31, part = tid >> 5;
    float v = 0.f;
    for (int b = part; b < NB1; b += 8) v += partial1[b * 32 + c];
    acc[part][c] = v;
    __syncthreads();
    if (tid < 32) {
        float t = 0.f;
#pragma unroll
        for (int p = 0; p < 8; ++p) t += acc[p][tid];
        tot[tid] = t;
    }
    __syncthreads();
    if (tid < CM1) {
        float inv = 1.f / (float)NPTS;
        float mu = tot[tid] * inv;
        float var = tot[CM1 + tid] * inv - mu * mu;
        float a = g1[tid] * rsqrtf(var + EPSBN);
        coef1[tid] = a;                       // scale
        coef1[CM1 + tid] = be1[tid] - mu * a; // shift
    }
}

// ---------------- wave-per-voxel VFE: recompute L1, run L2 ----------------
// FINAL=false: accumulate layer-2 BN stats. FINAL=true: bn2, maxes, scatter.
template <bool FINAL>
__global__ __launch_bounds__(256) void vfe_kernel(
    const float* __restrict__ feat,
    const float* __restrict__ W1g, const float* __restrict__ b1g,
    const float* __restrict__ coef1,
    const float* __restrict__ W2g, const float* __restrict__ b2g,
    const float* __restrict__ coef2,
    const int*  __restrict__ coord,
    float* __restrict__ partial2,
    float* __restrict__ out)
{
    __shared__ float sfeat[4][TP * CIN + 11];      // 245 -> 256 per wave
    alignas(16) __shared__ float scat[4][TP * 32]; // 1120 per wave, 16B-aligned rows
    __shared__ float smask[4][TP + 5];
    __shared__ float red2[4][2 * CM2];

    int tid = threadIdx.x, wid = tid >> 6, lane = tid & 63;
    int k = blockIdx.x * 4 + wid;                  // exact: NBV*4 == KVOX
    int tg = lane >> 4, c1 = lane & 15;

    // per-lane constants
    float w1r[CIN];
#pragma unroll
    for (int j = 0; j < CIN; ++j) w1r[j] = W1g[j * CM1 + c1];
    float b1r = b1g[c1];
    float a1r = coef1[c1], d1r = coef1[CM1 + c1];
    float w2r[32];
#pragma unroll
    for (int j = 0; j < 32; ++j) w2r[j] = W2g[j * CM2 + lane];
    float b2r = b2g[lane];
    float a2r = 0.f, d2r = 0.f;
    if constexpr (FINAL) { a2r = coef2[lane]; d2r = coef2[CM2 + lane]; }

    float* F = sfeat[wid];
    float* CT = scat[wid];
    float* M = smask[wid];

    // stage this voxel's 35x7 feature tile
    for (int i = lane; i < TP * CIN; i += 64)
        F[i] = feat[(size_t)k * (TP * CIN) + i];
    __syncthreads();

    // ---- phase 1: pw1 -> bn1, unmasked max over T, masked cat ----
    float maxv = -INFINITY;
#pragma unroll
    for (int it = 0; it < 9; ++it) {
        int t = tg + 4 * it;                       // covers t=0..34 exactly once
        if (t < TP) {
            float fv0 = F[t * CIN];
            float m7 = fv0;
            float acc = fmaf(fv0, w1r[0], b1r);
#pragma unroll
            for (int j = 1; j < CIN; ++j) {
                float fv = F[t * CIN + j];
                m7 = fmaxf(m7, fv);
                acc = fmaf(fv, w1r[j], acc);
            }
            float maskv = (m7 != 0.f) ? 1.f : 0.f;
            float pw = fmaxf(acc, 0.f);
            float bn = fmaf(pw, a1r, d1r);
            maxv = fmaxf(maxv, bn);                // agg1 uses UNMASKED bn
            CT[t * 32 + c1] = bn * maskv;
            if (c1 == 0) M[t] = maskv;
        }
    }
    maxv = fmaxf(maxv, __shfl_xor(maxv, 16));
    maxv = fmaxf(maxv, __shfl_xor(maxv, 32));      // agg1[c1] in all lanes
#pragma unroll
    for (int it = 0; it < 9; ++it) {
        int t = tg + 4 * it;
        if (t < TP) CT[t * 32 + 16 + c1] = maxv * M[t];
    }
    // all LDS deps above are within-wave (in-order LDS) — no block barrier needed

    // ---- phase 2: lane = output channel of the 32->64 linear ----
    float s_acc = 0.f, q_acc = 0.f;
    float agg2 = -INFINITY, v1 = -INFINITY, mmin = 1.f;
    for (int t = 0; t < TP; ++t) {
        const float4* r4 = reinterpret_cast<const float4*>(&CT[t * 32]);
        float acc0 = b2r, acc1 = 0.f;
#pragma unroll
        for (int i = 0; i < 8; i += 2) {
            float4 va = r4[i], vb = r4[i + 1];
            acc0 = fmaf(va.x, w2r[4 * i + 0], acc0);
            acc0 = fmaf(va.y, w2r[4 * i + 1], acc0);
            acc0 = fmaf(va.z, w2r[4 * i + 2], acc0);
            acc0 = fmaf(va.w, w2r[4 * i + 3], acc0);
            acc1 = fmaf(vb.x, w2r[4 * i + 4], acc1);
            acc1 = fmaf(vb.y, w2r[4 * i + 5], acc1);
            acc1 = fmaf(vb.z, w2r[4 * i + 6], acc1);
            acc1 = fmaf(vb.w, w2r[4 * i + 7], acc1);
        }
        float pw = fmaxf(acc0 + acc1, 0.f);
        if constexpr (!FINAL) {
            s_acc += pw; q_acc += pw * pw;
        } else {
            float bn = fmaf(pw, a2r, d2r);
            agg2 = fmaxf(agg2, bn);                // agg2 over UNMASKED bn2
            float mk = M[t];
            v1 = fmaxf(v1, bn * mk);               // voxelwise max of masked cat
            mmin = fminf(mmin, mk);
        }
    }

    if constexpr (!FINAL) {
        red2[wid][lane] = s_acc;
        red2[wid][CM2 + lane] = q_acc;
        __syncthreads();
        if (tid < 2 * CM2)
            partial2[(size_t)blockIdx.x * (2 * CM2) + tid] =
                red2[0][tid] + red2[1][tid] + red2[2][tid] + red2[3][tid];
    } else {
        float v2 = (mmin == 0.f) ? fmaxf(agg2, 0.f) : agg2; // masked max of agg2
        int cd = coord[k * 4 + 1], ch = coord[k * 4 + 2], cw = coord[k * 4 + 3];
        size_t base = ((((size_t)cd * HH) + ch) * WWID + cw) * 128;
        atomicAdd(&out[base + lane], v1);
        atomicAdd(&out[base + 64 + lane], v2);
    }
}

__global__ __launch_bounds__(1024) void reduce2_kernel(
    const float* __restrict__ partial2, const float* __restrict__ g2,
    const float* __restrict__ be2, float* __restrict__ coef2)
{
    __shared__ float acc[8][128];
    __shared__ float tot[128];
    int tid = threadIdx.x;
    int c = tid & 127, part = tid >> 7;
    float v = 0.f;
    for (int b = part; b < NBV; b += 8) v += partial2[(size_t)b * 128 + c];
    acc[part][c] = v;
    __syncthreads();
    if (tid < 128) {
        float t = 0.f;
#pragma unroll
        for (int p = 0; p < 8; ++p) t += acc[p][tid];
        tot[tid] = t;
    }
    __syncthreads();
    if (tid < CM2) {
        float inv = 1.f / (float)NPTS;
        float mu = tot[tid] * inv;
        float var = tot[CM2 + tid] * inv - mu * mu;
        float a = g2[tid] * rsqrtf(var + EPSBN);
        coef2[tid] = a;
        coef2[CM2 + tid] = be2[tid] - mu * a;
    }
}

extern "C" void kernel_launch(void* const* d_in, const int* in_sizes, int n_in,
                              void* d_out, int out_size, void* d_ws, size_t ws_size,
                              hipStream_t stream)
{
    const float* feat = (const float*)d_in[0];
    const int*   coord = (const int*)d_in[1];
    // d_in[2] = bs (==1, unused)
    const float* W1  = (const float*)d_in[3];
    const float* b1  = (const float*)d_in[4];
    const float* g1  = (const float*)d_in[5];
    const float* be1 = (const float*)d_in[6];
    const float* W2  = (const float*)d_in[7];
    const float* b2  = (const float*)d_in[8];
    const float* g2  = (const float*)d_in[9];
    const float* be2 = (const float*)d_in[10];
    float* out = (float*)d_out;

    float* wsf = (float*)d_ws;
    float* partial1 = wsf;                    // 1024*32   = 32768 floats
    float* partial2 = wsf + 32768;            // 3750*128  = 480000 floats
    float* coef1 = wsf + 32768 + 480000;      // 32 floats
    float* coef2 = coef1 + 32;                // 128 floats
    // total ws use: ~2.06 MB

    // the long pole: zero the 721 MB dense output grid
    hipMemsetAsync(d_out, 0, (size_t)out_size * sizeof(float), stream);

    stats1_kernel<<<NB1, 256, 0, stream>>>(feat, W1, b1, partial1);
    reduce1_kernel<<<1, 256, 0, stream>>>(partial1, g1, be1, coef1);
    vfe_kernel<false><<<NBV, 256, 0, stream>>>(feat, W1, b1, coef1, W2, b2,
                                               nullptr, nullptr, partial2, nullptr);
    reduce2_kernel<<<1, 1024, 0, stream>>>(partial2, g2, be2, coef2);
    vfe_kernel<true><<<NBV, 256, 0, stream>>>(feat, W1, b1, coef1, W2, b2,
                                              coef2, coord, nullptr, out);
}